// Round 17
// baseline (75.989 us; speedup 1.0000x reference)
//
#include <hip/hip_runtime.h>
#include <hip/hip_bf16.h>
#include <math.h>

#define Bb 8
#define Lq 1024
#define Pp 512   // = O
#define Dd 32
#define Kk 8
#define Mm 512
#define EPSf 1e-5f
#define TWO_LOG2E 2.885390081777927f   // 2*log2(e)

#define SPLIT 8
#define CHUNK (Lq / SPLIT)   // 128

typedef float f32x16 __attribute__((ext_vector_type(16)));
typedef float f32x4  __attribute__((ext_vector_type(4)));
typedef short s16x8  __attribute__((ext_vector_type(8)));
typedef unsigned int u32;

__device__ __forceinline__ ushort f2bf(float f) {
    union { float f; unsigned u; } v; v.f = f;
    unsigned r = (v.u + 0x7FFFu + ((v.u >> 16) & 1u)) >> 16;  // RNE
    return (ushort)r;
}
__device__ __forceinline__ u32 pack2bf(float a, float b) {
    return (u32)f2bf(a) | ((u32)f2bf(b) << 16);
}

// Butterfly sum over each 16-lane row; result valid in ALL lanes. (Validated R10/R12.)
__device__ __forceinline__ float rowsum16(float v) {
    v += __int_as_float(__builtin_amdgcn_update_dpp(0, __float_as_int(v), 0x0B1, 0xF, 0xF, true)); // quad_perm [1,0,3,2]
    v += __int_as_float(__builtin_amdgcn_update_dpp(0, __float_as_int(v), 0x04E, 0xF, 0xF, true)); // quad_perm [2,3,0,1]
    v += __int_as_float(__builtin_amdgcn_update_dpp(0, __float_as_int(v), 0x141, 0xF, 0xF, true)); // row_half_mirror
    v += __int_as_float(__builtin_amdgcn_update_dpp(0, __float_as_int(v), 0x140, 0xF, 0xF, true)); // row_mirror
    return v;
}

// ---------------- Kernel 1: R16 body @ 8 waves/SIMD ----------------
// grid = B*D*SPLIT = 2048 blocks (exactly 8 blocks/CU), 256 threads (4 waves).
// (256,8): measured VGPR=40 at R16 -> fits the 64-reg budget; LDS 11.25KB*8 = 90KB fits.
// 128-l chunk in registers: bfr[8] (32 VGPR) + w8[8], read from LDS ONCE.
// Per nt: ONE predicated ds_read_b128 A-frag from pre-converted yd_lds. Zero other hot DS.
__global__ __launch_bounds__(256, 8) void k1_scores_v(
    const float* __restrict__ x, const float* __restrict__ xd,
    const float* __restrict__ yd,
    const float* __restrict__ gng, const float* __restrict__ gnb,
    const float* __restrict__ gnm, const float* __restrict__ gnv,
    float* __restrict__ vpart)
{
    __shared__ __align__(16) ushort xd_s[CHUNK][8];   // bf16, pre-scaled, 2 KB
    __shared__ float w_s[CHUNK];                      // 0.5 KB
    __shared__ float wred[4];
    __shared__ __align__(16) ushort yd_lds[Pp * 8];   // bf16 yd slice, 8 KB

    int bid = blockIdx.x;
    int s = bid & (SPLIT - 1);
    int d = (bid >> 3) & 31;
    int b = bid >> 8;
    int tid  = threadIdx.x;
    int lane = tid & 63;
    int wid  = tid >> 6;
    int q    = lane & 15;     // l-col selector within tile
    int g    = lane >> 4;     // k-octet group 0..3 (also p-row group in D)

    float inv_g = gng[d] * rsqrtf(gnv[d] + EPSf);
    float cs    = TWO_LOG2E * inv_g;
    float biasp = TWO_LOG2E * (gnb[d] - gnm[d] * inv_g);
    float Cb    = __builtin_amdgcn_exp2f(biasp);   // bias folded multiplicatively

    // stage xd chunk (scaled bf16) + w
    float w = 0.f;
    if (tid < CHUNK) {
        int lg = s * CHUNK + tid;
        const float* row = xd + ((size_t)(b * Lq + lg) * Dd + d) * Kk;
        float4 a0 = ((const float4*)row)[0];
        float4 a1 = ((const float4*)row)[1];
        s16x8 rv;
        rv[0] = (short)f2bf(a0.x * cs); rv[1] = (short)f2bf(a0.y * cs);
        rv[2] = (short)f2bf(a0.z * cs); rv[3] = (short)f2bf(a0.w * cs);
        rv[4] = (short)f2bf(a1.x * cs); rv[5] = (short)f2bf(a1.y * cs);
        rv[6] = (short)f2bf(a1.z * cs); rv[7] = (short)f2bf(a1.w * cs);
        *((s16x8*)xd_s[tid]) = rv;
        w = x[((size_t)(b * Lq + lg)) * Dd + d];
        w_s[tid] = w;
    }
    // stage yd slice (bf16), 2 rows per thread (validated R13/R16)
    for (int p = tid; p < Pp; p += 256) {
        const float* yr = yd + ((size_t)(b * Pp + p) * Dd + d) * Kk;
        float4 y0 = ((const float4*)yr)[0];
        float4 y1 = ((const float4*)yr)[1];
        s16x8 rv;
        rv[0] = (short)f2bf(y0.x); rv[1] = (short)f2bf(y0.y);
        rv[2] = (short)f2bf(y0.z); rv[3] = (short)f2bf(y0.w);
        rv[4] = (short)f2bf(y1.x); rv[5] = (short)f2bf(y1.y);
        rv[6] = (short)f2bf(y1.z); rv[7] = (short)f2bf(y1.w);
        *((s16x8*)&yd_lds[p * 8]) = rv;
    }
    float wsum = w;
    #pragma unroll
    for (int m = 1; m < 64; m <<= 1) wsum += __shfl_xor(wsum, m);
    if (lane == 0) wred[wid] = wsum;
    __syncthreads();
    float S_w = wred[0] + wred[1] + wred[2] + wred[3];

    // ---- hoist the whole chunk into registers (once per wave) ----
    s16x8 bfr[8];
    float w8[8];
    #pragma unroll
    for (int lt = 0; lt < 8; ++lt) {
        bfr[lt] = *((const s16x8*)xd_s[lt * 16 + q]);   // unpredicated broadcast (safe: afr zeros k>=8)
        w8[lt]  = w_s[lt * 16 + q];
    }

    for (int nt = 0; nt < 8; ++nt) {
        int p0 = wid * 128 + nt * 16;
        s16x8 afr = {};
        if (g == 0) afr = *((const s16x8*)&yd_lds[(p0 + q) * 8]);

        f32x4 acc = {0.f, 0.f, 0.f, 0.f};
        #pragma unroll
        for (int lt = 0; lt < 8; ++lt) {
            f32x4 z = {};
            f32x4 dd = __builtin_amdgcn_mfma_f32_16x16x32_bf16(afr, bfr[lt], z, 0, 0, 0);
            float wl = w8[lt];
            #pragma unroll
            for (int r = 0; r < 4; ++r) {
                float e  = __builtin_amdgcn_exp2f(dd[r]);
                float t  = fmaf(e, Cb, 1.0f);
                float rc = __builtin_amdgcn_rcpf(t);
                acc[r] = fmaf(wl, rc, acc[r]);
            }
        }

        // reduce over l-cols (lanes q=0..15) on the VALU pipe via DPP butterfly
        float4 o;
        #pragma unroll
        for (int r = 0; r < 4; ++r) {
            float v = rowsum16(acc[r]);
            ((float*)&o)[r] = S_w - 2.0f * v;
        }
        if (q == 0) {
            // lane (q=0, g) holds rows p0 + g*4 + (0..3) -> contiguous float4
            size_t base = ((size_t)(s * Bb + b) * Dd + d) * Pp + p0 + g * 4;
            *(float4*)(vpart + base) = o;
        }
    }
}

// ---------------- Kernel 2: MFMA FFN (unchanged, proven correct) ----------------
__device__ __forceinline__ float gelu_t(float x) {
    float x2 = x * x;
    float up = x * fmaf(x2, 0.10294387f, 2.3022118f);  // 2*log2e*0.79788456*(1, 0.044715)
    float e  = __builtin_amdgcn_exp2f(up);
    float rc = __builtin_amdgcn_rcpf(e + 1.0f);
    return x * (1.0f - rc);
}

__global__ __launch_bounds__(256) void k2_ffn(
    const float* __restrict__ vpart,
    const float* __restrict__ n1g, const float* __restrict__ n1b,
    const float* __restrict__ n1m, const float* __restrict__ n1v,
    const float* __restrict__ w1, const float* __restrict__ b1,
    const float* __restrict__ w2, const float* __restrict__ b2,
    const float* __restrict__ n2g, const float* __restrict__ n2b,
    const float* __restrict__ n2m, const float* __restrict__ n2v,
    float* __restrict__ out)
{
    __shared__ __align__(16) ushort w2l[Dd * Mm];   // 32 KB, W2' bf16, XOR-swizzled
    __shared__ __align__(16) ushort xr_t[32 * 40];  // [p][d] bf16, stride 40 (2.5 KB)
    __shared__ float resid[32 * 33];                // [p][d] f32 (4.2 KB)
    __shared__ float red[4][32 * 33];               // partial out [w][p][d] (16.9 KB)

    int bid = blockIdx.x;
    int b  = bid >> 4;
    int p0 = (bid & 15) * 32;
    int tid  = threadIdx.x;
    int lane = tid & 63;
    int wid  = tid >> 6;
    int lo   = lane & 31;
    int hi   = lane >> 5;

    // ---- stage W2' = w2[d][m] * inv2[d] as bf16, swizzled ----
    {
        int d  = tid >> 3;
        int mb = tid & 7;
        float inv2 = n2g[d] * rsqrtf(n2v[d] + EPSf);
        const float* wr = w2 + (size_t)d * Mm + mb * 64;
        u32 base = (u32)(d * 1024 + mb * 128);
        u32 swz  = (u32)((d & 7) << 4);
        #pragma unroll
        for (int j = 0; j < 8; ++j) {
            float4 f0 = ((const float4*)wr)[j * 2];
            float4 f1 = ((const float4*)wr)[j * 2 + 1];
            uint4 qd;
            qd.x = pack2bf(f0.x * inv2, f0.y * inv2);
            qd.y = pack2bf(f0.z * inv2, f0.w * inv2);
            qd.z = pack2bf(f1.x * inv2, f1.y * inv2);
            qd.w = pack2bf(f1.z * inv2, f1.w * inv2);
            *(uint4*)((char*)w2l + ((base + j * 16) ^ swz)) = qd;
        }
    }

    // ---- phase A: reduce vpart (SPLIT partials) -> n1 -> xr_t(bf16) + resid(f32) ----
    {
        int d  = tid >> 3;
        int pq = tid & 7;
        size_t vb = ((size_t)b * Dd + d) * Pp + p0 + pq * 4;
        float4 sum = {0.f, 0.f, 0.f, 0.f};
        #pragma unroll
        for (int s = 0; s < SPLIT; ++s) {
            float4 t = *(const float4*)(vpart + vb + (size_t)s * (Bb * Dd * Pp));
            sum.x += t.x; sum.y += t.y; sum.z += t.z; sum.w += t.w;
        }
        float inv1 = n1g[d] * rsqrtf(n1v[d] + EPSf);
        float bs1  = n1b[d] - n1m[d] * inv1;
        float inv2 = n2g[d] * rsqrtf(n2v[d] + EPSf);
        float bs2  = n2b[d] - n2m[d] * inv2;
        float b2d  = b2[d];
        float xv[4] = {sum.x, sum.y, sum.z, sum.w};
        #pragma unroll
        for (int j = 0; j < 4; ++j) {
            float xrv = fmaf(xv[j], inv1, bs1);
            int pl = pq * 4 + j;
            xr_t[pl * 40 + d] = f2bf(xrv);
            resid[pl * 33 + d] = fmaf(xrv + b2d, inv2, bs2);
        }
    }
    __syncthreads();

    // ---- phase B+C per wave: h = gelu(W1@xr + b1); out += W2'@h over this wave's m ----
    s16x8 bx0 = *(const s16x8*)((const char*)xr_t + lo * 80 + hi * 16);       // k=d 0..15
    s16x8 bx1 = *(const s16x8*)((const char*)xr_t + lo * 80 + 32 + hi * 16);  // k=d 16..31
    s16x8 bone = {};
    if (hi == 0) bone[0] = (short)0x3F80;   // B[k=32][*] = 1 for bias MFMA

    f32x16 oacc = {};
    #pragma unroll
    for (int i = 0; i < 4; ++i) {
        int mt = wid * 4 + i;
        int m0 = mt * 32;
        const float* w1r = w1 + (size_t)(m0 + lo) * Dd + hi * 8;
        float4 c0 = ((const float4*)w1r)[0];
        float4 c1 = ((const float4*)w1r)[1];
        float4 c2 = ((const float4*)(w1r + 16))[0];
        float4 c3 = ((const float4*)(w1r + 16))[1];
        s16x8 a0, a1;
        a0[0] = (short)f2bf(c0.x); a0[1] = (short)f2bf(c0.y);
        a0[2] = (short)f2bf(c0.z); a0[3] = (short)f2bf(c0.w);
        a0[4] = (short)f2bf(c1.x); a0[5] = (short)f2bf(c1.y);
        a0[6] = (short)f2bf(c1.z); a0[7] = (short)f2bf(c1.w);
        a1[0] = (short)f2bf(c2.x); a1[1] = (short)f2bf(c2.y);
        a1[2] = (short)f2bf(c2.z); a1[3] = (short)f2bf(c2.w);
        a1[4] = (short)f2bf(c3.x); a1[5] = (short)f2bf(c3.y);
        a1[6] = (short)f2bf(c3.z); a1[7] = (short)f2bf(c3.w);
        s16x8 ab = {};
        float b1v = b1[m0 + lo];
        if (hi == 0) ab[0] = (short)f2bf(b1v);   // A[m][k=32] = b1[m]

        f32x16 z = {};
        f32x16 hc = __builtin_amdgcn_mfma_f32_32x32x16_bf16(a0, bx0, z, 0, 0, 0);
        hc = __builtin_amdgcn_mfma_f32_32x32x16_bf16(a1, bx1, hc, 0, 0, 0);
        hc = __builtin_amdgcn_mfma_f32_32x32x16_bf16(ab, bone, hc, 0, 0, 0);

        float gg[16];
        #pragma unroll
        for (int r = 0; r < 16; ++r) gg[r] = gelu_t(hc[r]);

        #pragma unroll
        for (int kt = 0; kt < 2; ++kt) {
            int gb = kt * 8;
            u32 A0 = pack2bf(gg[gb + 0], gg[gb + 1]);
            u32 A1 = pack2bf(gg[gb + 2], gg[gb + 3]);
            u32 A2 = pack2bf(gg[gb + 4], gg[gb + 5]);
            u32 A3 = pack2bf(gg[gb + 6], gg[gb + 7]);
            int lo4 = lo * 4;
            u32 A2lo = (u32)__builtin_amdgcn_ds_bpermute(lo4,       (int)A2);
            u32 A3lo = (u32)__builtin_amdgcn_ds_bpermute(lo4,       (int)A3);
            u32 A0hi = (u32)__builtin_amdgcn_ds_bpermute(lo4 + 128, (int)A0);
            u32 A1hi = (u32)__builtin_amdgcn_ds_bpermute(lo4 + 128, (int)A1);
            union { uint4 u; s16x8 v; } hf;
            hf.u.x = hi ? A2lo : A0;
            hf.u.y = hi ? A3lo : A1;
            hf.u.z = hi ? A2 : A0hi;
            hf.u.w = hi ? A3 : A1hi;
            u32 raddr = (u32)((lo * 1024 + mt * 64 + kt * 32 + hi * 16) ^ ((lo & 7) << 4));
            s16x8 wf = *(const s16x8*)((const char*)w2l + raddr);
            oacc = __builtin_amdgcn_mfma_f32_32x32x16_bf16(wf, hf.v, oacc, 0, 0, 0);
        }
    }

    {
        float* rw = red[wid];
        #pragma unroll
        for (int r = 0; r < 16; ++r) {
            int dr = (r & 3) + ((r >> 2) << 3) + (hi << 2);
            rw[lo * 33 + dr] = oacc[r];
        }
    }
    __syncthreads();

    {
        int d  = tid & 31;
        int pg = tid >> 5;
        #pragma unroll
        for (int j = 0; j < 4; ++j) {
            int pl = pg * 4 + j;
            int idx = pl * 33 + d;
            float v = red[0][idx] + red[1][idx] + red[2][idx] + red[3][idx] + resid[idx];
            out[((size_t)(b * Pp + p0 + pl)) * Dd + d] = v;
        }
    }
}

extern "C" void kernel_launch(void* const* d_in, const int* in_sizes, int n_in,
                              void* d_out, int out_size, void* d_ws, size_t ws_size,
                              hipStream_t stream) {
    const float* x    = (const float*)d_in[0];
    const float* xd   = (const float*)d_in[1];
    const float* yd   = (const float*)d_in[2];
    const float* gng  = (const float*)d_in[3];
    const float* gnb  = (const float*)d_in[4];
    const float* gnm  = (const float*)d_in[5];
    const float* gnv  = (const float*)d_in[6];
    const float* n1g  = (const float*)d_in[7];
    const float* n1b  = (const float*)d_in[8];
    const float* n1m  = (const float*)d_in[9];
    const float* n1v  = (const float*)d_in[10];
    const float* w1   = (const float*)d_in[11];
    const float* b1   = (const float*)d_in[12];
    const float* w2   = (const float*)d_in[13];
    const float* b2   = (const float*)d_in[14];
    const float* n2g  = (const float*)d_in[15];
    const float* n2b  = (const float*)d_in[16];
    const float* n2m  = (const float*)d_in[17];
    const float* n2v  = (const float*)d_in[18];

    float* vpart = (float*)d_ws;   // SPLIT * B * D * P f32 = 4 MB
    float* outf  = (float*)d_out;

    k1_scores_v<<<Bb * Dd * SPLIT, 256, 0, stream>>>(
        x, xd, yd, gng, gnb, gnm, gnv, vpart);
    k2_ffn<<<Bb * (Pp / 32), 256, 0, stream>>>(
        vpart, n1g, n1b, n1m, n1v, w1, b1, w2, b2, n2g, n2b, n2m, n2v, outf);
}

// Round 18
// 52.389 us; speedup vs baseline: 1.4505x; 1.4505x over previous
//
#include <hip/hip_runtime.h>
#include <hip/hip_bf16.h>
#include <math.h>

#define Bb 8
#define Lq 1024
#define Pp 512   // = O
#define Dd 32
#define Kk 8
#define Mm 512
#define EPSf 1e-5f
#define TWO_LOG2E 2.885390081777927f   // 2*log2(e)

#define SPLIT 16
#define CHUNK (Lq / SPLIT)   // 64

typedef float f32x16 __attribute__((ext_vector_type(16)));
typedef float f32x4  __attribute__((ext_vector_type(4)));
typedef short s16x8  __attribute__((ext_vector_type(8)));
typedef unsigned int u32;

__device__ __forceinline__ ushort f2bf(float f) {
    union { float f; unsigned u; } v; v.f = f;
    unsigned r = (v.u + 0x7FFFu + ((v.u >> 16) & 1u)) >> 16;  // RNE
    return (ushort)r;
}
__device__ __forceinline__ u32 pack2bf(float a, float b) {
    return (u32)f2bf(a) | ((u32)f2bf(b) << 16);
}

// Butterfly sum over each 16-lane row; result valid in ALL lanes. (Validated R10/R12.)
__device__ __forceinline__ float rowsum16(float v) {
    v += __int_as_float(__builtin_amdgcn_update_dpp(0, __float_as_int(v), 0x0B1, 0xF, 0xF, true)); // quad_perm [1,0,3,2]
    v += __int_as_float(__builtin_amdgcn_update_dpp(0, __float_as_int(v), 0x04E, 0xF, 0xF, true)); // quad_perm [2,3,0,1]
    v += __int_as_float(__builtin_amdgcn_update_dpp(0, __float_as_int(v), 0x141, 0xF, 0xF, true)); // row_half_mirror
    v += __int_as_float(__builtin_amdgcn_update_dpp(0, __float_as_int(v), 0x140, 0xF, 0xF, true)); // row_mirror
    return v;
}

// ---------------- Kernel 1: R14 body @ 8 waves/SIMD (proven 32-reg, clean) ----------------
// grid = B*D*SPLIT = 4096 blocks = 16 blocks/CU -> exactly two FULL rounds at cap 8.
// Whole 64-l chunk in registers: bfr[4] (16 VGPR) + w8[4], read from LDS ONCE.
// nt-loop (8 p-tiles): prefetched A-frag global load, 4 MFMA + 16 sigma, DPP epilogue.
// ZERO DS ops in the hot path.
__global__ __launch_bounds__(256, 8) void k1_scores_v(
    const float* __restrict__ x, const float* __restrict__ xd,
    const float* __restrict__ yd,
    const float* __restrict__ gng, const float* __restrict__ gnb,
    const float* __restrict__ gnm, const float* __restrict__ gnv,
    float* __restrict__ vpart)
{
    __shared__ __align__(16) ushort xd_s[CHUNK][8];   // bf16, pre-scaled, 1 KB
    __shared__ float w_s[CHUNK];                      // 0.25 KB
    __shared__ float wred[4];

    int bid = blockIdx.x;
    int s = bid & (SPLIT - 1);
    int d = (bid >> 4) & 31;
    int b = bid >> 9;
    int tid  = threadIdx.x;
    int lane = tid & 63;
    int wid  = tid >> 6;
    int q    = lane & 15;     // l-col selector within tile
    int g    = lane >> 4;     // k-octet group 0..3 (also p-row group in D)

    float inv_g = gng[d] * rsqrtf(gnv[d] + EPSf);
    float cs    = TWO_LOG2E * inv_g;
    float biasp = TWO_LOG2E * (gnb[d] - gnm[d] * inv_g);
    float Cb    = __builtin_amdgcn_exp2f(biasp);   // bias folded multiplicatively

    float w = 0.f;
    if (tid < CHUNK) {
        int lg = s * CHUNK + tid;
        const float* row = xd + ((size_t)(b * Lq + lg) * Dd + d) * Kk;
        float4 a0 = ((const float4*)row)[0];
        float4 a1 = ((const float4*)row)[1];
        s16x8 rv;
        rv[0] = (short)f2bf(a0.x * cs); rv[1] = (short)f2bf(a0.y * cs);
        rv[2] = (short)f2bf(a0.z * cs); rv[3] = (short)f2bf(a0.w * cs);
        rv[4] = (short)f2bf(a1.x * cs); rv[5] = (short)f2bf(a1.y * cs);
        rv[6] = (short)f2bf(a1.z * cs); rv[7] = (short)f2bf(a1.w * cs);
        *((s16x8*)xd_s[tid]) = rv;
        w = x[((size_t)(b * Lq + lg)) * Dd + d];
        w_s[tid] = w;
    }
    float wsum = w;
    #pragma unroll
    for (int m = 1; m < 64; m <<= 1) wsum += __shfl_xor(wsum, m);
    if (lane == 0) wred[wid] = wsum;
    __syncthreads();
    float S_w = wred[0] + wred[1] + wred[2] + wred[3];

    // ---- hoist the whole chunk into registers (once per wave) ----
    s16x8 bfr[4];
    float w8[4];
    #pragma unroll
    for (int lt = 0; lt < 4; ++lt) {
        bfr[lt] = *((const s16x8*)xd_s[lt * 16 + q]);   // unpredicated broadcast (safe: afr zeros k>=8)
        w8[lt]  = w_s[lt * 16 + q];
    }

    // ---- prefetched A-frag pipeline over 8 nt-tiles ----
    float4 ya = {0,0,0,0}, yb = {0,0,0,0};
    if (g == 0) {
        const float* yr = yd + ((size_t)(b * Pp + wid * 128 + q) * Dd + d) * Kk;
        ya = ((const float4*)yr)[0];
        yb = ((const float4*)yr)[1];
    }

    for (int nt = 0; nt < 8; ++nt) {
        s16x8 afr = {};
        if (g == 0) {
            afr[0] = (short)f2bf(ya.x); afr[1] = (short)f2bf(ya.y);
            afr[2] = (short)f2bf(ya.z); afr[3] = (short)f2bf(ya.w);
            afr[4] = (short)f2bf(yb.x); afr[5] = (short)f2bf(yb.y);
            afr[6] = (short)f2bf(yb.z); afr[7] = (short)f2bf(yb.w);
        }
        float4 yan = {0,0,0,0}, ybn = {0,0,0,0};
        if (nt < 7 && g == 0) {
            const float* yr = yd + ((size_t)(b * Pp + wid * 128 + (nt + 1) * 16 + q) * Dd + d) * Kk;
            yan = ((const float4*)yr)[0];
            ybn = ((const float4*)yr)[1];
        }

        f32x4 acc = {0.f, 0.f, 0.f, 0.f};
        #pragma unroll
        for (int lt = 0; lt < 4; ++lt) {
            f32x4 z = {};
            f32x4 dd = __builtin_amdgcn_mfma_f32_16x16x32_bf16(afr, bfr[lt], z, 0, 0, 0);
            float wl = w8[lt];
            #pragma unroll
            for (int r = 0; r < 4; ++r) {
                float e  = __builtin_amdgcn_exp2f(dd[r]);
                float t  = fmaf(e, Cb, 1.0f);
                float rc = __builtin_amdgcn_rcpf(t);
                acc[r] = fmaf(wl, rc, acc[r]);
            }
        }

        // reduce over l-cols (lanes q=0..15) on the VALU pipe via DPP butterfly
        float4 o;
        #pragma unroll
        for (int r = 0; r < 4; ++r) {
            float v = rowsum16(acc[r]);
            ((float*)&o)[r] = S_w - 2.0f * v;
        }
        if (q == 0) {
            // lane (q=0, g) holds rows p0 + g*4 + (0..3) -> contiguous float4
            size_t base = ((size_t)(s * Bb + b) * Dd + d) * Pp + wid * 128 + nt * 16 + g * 4;
            *(float4*)(vpart + base) = o;
        }
        ya = yan; yb = ybn;
    }
}

// ---------------- Kernel 2: MFMA FFN (unchanged, proven correct) ----------------
__device__ __forceinline__ float gelu_t(float x) {
    float x2 = x * x;
    float up = x * fmaf(x2, 0.10294387f, 2.3022118f);  // 2*log2e*0.79788456*(1, 0.044715)
    float e  = __builtin_amdgcn_exp2f(up);
    float rc = __builtin_amdgcn_rcpf(e + 1.0f);
    return x * (1.0f - rc);
}

__global__ __launch_bounds__(256) void k2_ffn(
    const float* __restrict__ vpart,
    const float* __restrict__ n1g, const float* __restrict__ n1b,
    const float* __restrict__ n1m, const float* __restrict__ n1v,
    const float* __restrict__ w1, const float* __restrict__ b1,
    const float* __restrict__ w2, const float* __restrict__ b2,
    const float* __restrict__ n2g, const float* __restrict__ n2b,
    const float* __restrict__ n2m, const float* __restrict__ n2v,
    float* __restrict__ out)
{
    __shared__ __align__(16) ushort w2l[Dd * Mm];   // 32 KB, W2' bf16, XOR-swizzled
    __shared__ __align__(16) ushort xr_t[32 * 40];  // [p][d] bf16, stride 40 (2.5 KB)
    __shared__ float resid[32 * 33];                // [p][d] f32 (4.2 KB)
    __shared__ float red[4][32 * 33];               // partial out [w][p][d] (16.9 KB)

    int bid = blockIdx.x;
    int b  = bid >> 4;
    int p0 = (bid & 15) * 32;
    int tid  = threadIdx.x;
    int lane = tid & 63;
    int wid  = tid >> 6;
    int lo   = lane & 31;
    int hi   = lane >> 5;

    // ---- stage W2' = w2[d][m] * inv2[d] as bf16, swizzled ----
    {
        int d  = tid >> 3;
        int mb = tid & 7;
        float inv2 = n2g[d] * rsqrtf(n2v[d] + EPSf);
        const float* wr = w2 + (size_t)d * Mm + mb * 64;
        u32 base = (u32)(d * 1024 + mb * 128);
        u32 swz  = (u32)((d & 7) << 4);
        #pragma unroll
        for (int j = 0; j < 8; ++j) {
            float4 f0 = ((const float4*)wr)[j * 2];
            float4 f1 = ((const float4*)wr)[j * 2 + 1];
            uint4 qd;
            qd.x = pack2bf(f0.x * inv2, f0.y * inv2);
            qd.y = pack2bf(f0.z * inv2, f0.w * inv2);
            qd.z = pack2bf(f1.x * inv2, f1.y * inv2);
            qd.w = pack2bf(f1.z * inv2, f1.w * inv2);
            *(uint4*)((char*)w2l + ((base + j * 16) ^ swz)) = qd;
        }
    }

    // ---- phase A: reduce vpart (SPLIT partials) -> n1 -> xr_t(bf16) + resid(f32) ----
    {
        int d  = tid >> 3;
        int pq = tid & 7;
        size_t vb = ((size_t)b * Dd + d) * Pp + p0 + pq * 4;
        float4 sum = {0.f, 0.f, 0.f, 0.f};
        #pragma unroll
        for (int s = 0; s < SPLIT; ++s) {
            float4 t = *(const float4*)(vpart + vb + (size_t)s * (Bb * Dd * Pp));
            sum.x += t.x; sum.y += t.y; sum.z += t.z; sum.w += t.w;
        }
        float inv1 = n1g[d] * rsqrtf(n1v[d] + EPSf);
        float bs1  = n1b[d] - n1m[d] * inv1;
        float inv2 = n2g[d] * rsqrtf(n2v[d] + EPSf);
        float bs2  = n2b[d] - n2m[d] * inv2;
        float b2d  = b2[d];
        float xv[4] = {sum.x, sum.y, sum.z, sum.w};
        #pragma unroll
        for (int j = 0; j < 4; ++j) {
            float xrv = fmaf(xv[j], inv1, bs1);
            int pl = pq * 4 + j;
            xr_t[pl * 40 + d] = f2bf(xrv);
            resid[pl * 33 + d] = fmaf(xrv + b2d, inv2, bs2);
        }
    }
    __syncthreads();

    // ---- phase B+C per wave: h = gelu(W1@xr + b1); out += W2'@h over this wave's m ----
    s16x8 bx0 = *(const s16x8*)((const char*)xr_t + lo * 80 + hi * 16);       // k=d 0..15
    s16x8 bx1 = *(const s16x8*)((const char*)xr_t + lo * 80 + 32 + hi * 16);  // k=d 16..31
    s16x8 bone = {};
    if (hi == 0) bone[0] = (short)0x3F80;   // B[k=32][*] = 1 for bias MFMA

    f32x16 oacc = {};
    #pragma unroll
    for (int i = 0; i < 4; ++i) {
        int mt = wid * 4 + i;
        int m0 = mt * 32;
        const float* w1r = w1 + (size_t)(m0 + lo) * Dd + hi * 8;
        float4 c0 = ((const float4*)w1r)[0];
        float4 c1 = ((const float4*)w1r)[1];
        float4 c2 = ((const float4*)(w1r + 16))[0];
        float4 c3 = ((const float4*)(w1r + 16))[1];
        s16x8 a0, a1;
        a0[0] = (short)f2bf(c0.x); a0[1] = (short)f2bf(c0.y);
        a0[2] = (short)f2bf(c0.z); a0[3] = (short)f2bf(c0.w);
        a0[4] = (short)f2bf(c1.x); a0[5] = (short)f2bf(c1.y);
        a0[6] = (short)f2bf(c1.z); a0[7] = (short)f2bf(c1.w);
        a1[0] = (short)f2bf(c2.x); a1[1] = (short)f2bf(c2.y);
        a1[2] = (short)f2bf(c2.z); a1[3] = (short)f2bf(c2.w);
        a1[4] = (short)f2bf(c3.x); a1[5] = (short)f2bf(c3.y);
        a1[6] = (short)f2bf(c3.z); a1[7] = (short)f2bf(c3.w);
        s16x8 ab = {};
        float b1v = b1[m0 + lo];
        if (hi == 0) ab[0] = (short)f2bf(b1v);   // A[m][k=32] = b1[m]

        f32x16 z = {};
        f32x16 hc = __builtin_amdgcn_mfma_f32_32x32x16_bf16(a0, bx0, z, 0, 0, 0);
        hc = __builtin_amdgcn_mfma_f32_32x32x16_bf16(a1, bx1, hc, 0, 0, 0);
        hc = __builtin_amdgcn_mfma_f32_32x32x16_bf16(ab, bone, hc, 0, 0, 0);

        float gg[16];
        #pragma unroll
        for (int r = 0; r < 16; ++r) gg[r] = gelu_t(hc[r]);

        #pragma unroll
        for (int kt = 0; kt < 2; ++kt) {
            int gb = kt * 8;
            u32 A0 = pack2bf(gg[gb + 0], gg[gb + 1]);
            u32 A1 = pack2bf(gg[gb + 2], gg[gb + 3]);
            u32 A2 = pack2bf(gg[gb + 4], gg[gb + 5]);
            u32 A3 = pack2bf(gg[gb + 6], gg[gb + 7]);
            int lo4 = lo * 4;
            u32 A2lo = (u32)__builtin_amdgcn_ds_bpermute(lo4,       (int)A2);
            u32 A3lo = (u32)__builtin_amdgcn_ds_bpermute(lo4,       (int)A3);
            u32 A0hi = (u32)__builtin_amdgcn_ds_bpermute(lo4 + 128, (int)A0);
            u32 A1hi = (u32)__builtin_amdgcn_ds_bpermute(lo4 + 128, (int)A1);
            union { uint4 u; s16x8 v; } hf;
            hf.u.x = hi ? A2lo : A0;
            hf.u.y = hi ? A3lo : A1;
            hf.u.z = hi ? A2 : A0hi;
            hf.u.w = hi ? A3 : A1hi;
            u32 raddr = (u32)((lo * 1024 + mt * 64 + kt * 32 + hi * 16) ^ ((lo & 7) << 4));
            s16x8 wf = *(const s16x8*)((const char*)w2l + raddr);
            oacc = __builtin_amdgcn_mfma_f32_32x32x16_bf16(wf, hf.v, oacc, 0, 0, 0);
        }
    }

    {
        float* rw = red[wid];
        #pragma unroll
        for (int r = 0; r < 16; ++r) {
            int dr = (r & 3) + ((r >> 2) << 3) + (hi << 2);
            rw[lo * 33 + dr] = oacc[r];
        }
    }
    __syncthreads();

    {
        int d  = tid & 31;
        int pg = tid >> 5;
        #pragma unroll
        for (int j = 0; j < 4; ++j) {
            int pl = pg * 4 + j;
            int idx = pl * 33 + d;
            float v = red[0][idx] + red[1][idx] + red[2][idx] + red[3][idx] + resid[idx];
            out[((size_t)(b * Pp + p0 + pl)) * Dd + d] = v;
        }
    }
}

extern "C" void kernel_launch(void* const* d_in, const int* in_sizes, int n_in,
                              void* d_out, int out_size, void* d_ws, size_t ws_size,
                              hipStream_t stream) {
    const float* x    = (const float*)d_in[0];
    const float* xd   = (const float*)d_in[1];
    const float* yd   = (const float*)d_in[2];
    const float* gng  = (const float*)d_in[3];
    const float* gnb  = (const float*)d_in[4];
    const float* gnm  = (const float*)d_in[5];
    const float* gnv  = (const float*)d_in[6];
    const float* n1g  = (const float*)d_in[7];
    const float* n1b  = (const float*)d_in[8];
    const float* n1m  = (const float*)d_in[9];
    const float* n1v  = (const float*)d_in[10];
    const float* w1   = (const float*)d_in[11];
    const float* b1   = (const float*)d_in[12];
    const float* w2   = (const float*)d_in[13];
    const float* b2   = (const float*)d_in[14];
    const float* n2g  = (const float*)d_in[15];
    const float* n2b  = (const float*)d_in[16];
    const float* n2m  = (const float*)d_in[17];
    const float* n2v  = (const float*)d_in[18];

    float* vpart = (float*)d_ws;   // SPLIT * B * D * P f32 = 8 MB
    float* outf  = (float*)d_out;

    k1_scores_v<<<Bb * Dd * SPLIT, 256, 0, stream>>>(
        x, xd, yd, gng, gnb, gnm, gnv, vpart);
    k2_ffn<<<Bb * (Pp / 32), 256, 0, stream>>>(
        vpart, n1g, n1b, n1m, n1v, w1, b1, w2, b2, n2g, n2b, n2m, n2v, outf);
}

// Round 19
// 46.591 us; speedup vs baseline: 1.6310x; 1.1244x over previous
//
#include <hip/hip_runtime.h>
#include <hip/hip_bf16.h>
#include <math.h>

#define Bb 8
#define Lq 1024
#define Pp 512   // = O
#define Dd 32
#define Kk 8
#define Mm 512
#define EPSf 1e-5f
#define TWO_LOG2E 2.885390081777927f   // 2*log2(e)

#define SPLIT 8
#define CHUNK (Lq / SPLIT)   // 128

typedef float f32x16 __attribute__((ext_vector_type(16)));
typedef float f32x4  __attribute__((ext_vector_type(4)));
typedef short s16x8  __attribute__((ext_vector_type(8)));
typedef unsigned int u32;

__device__ __forceinline__ ushort f2bf(float f) {
    union { float f; unsigned u; } v; v.f = f;
    unsigned r = (v.u + 0x7FFFu + ((v.u >> 16) & 1u)) >> 16;  // RNE
    return (ushort)r;
}
__device__ __forceinline__ u32 pack2bf(float a, float b) {
    return (u32)f2bf(a) | ((u32)f2bf(b) << 16);
}

// Butterfly sum over each 16-lane row; result valid in ALL lanes. (Validated R10/R12.)
__device__ __forceinline__ float rowsum16(float v) {
    v += __int_as_float(__builtin_amdgcn_update_dpp(0, __float_as_int(v), 0x0B1, 0xF, 0xF, true)); // quad_perm [1,0,3,2]
    v += __int_as_float(__builtin_amdgcn_update_dpp(0, __float_as_int(v), 0x04E, 0xF, 0xF, true)); // quad_perm [2,3,0,1]
    v += __int_as_float(__builtin_amdgcn_update_dpp(0, __float_as_int(v), 0x141, 0xF, 0xF, true)); // row_half_mirror
    v += __int_as_float(__builtin_amdgcn_update_dpp(0, __float_as_int(v), 0x140, 0xF, 0xF, true)); // row_mirror
    return v;
}

// ---------------- Kernel 1: all-register hot loop (R12, best measured: 46.6 us total) ----------------
// grid = B*D*SPLIT = 2048 blocks, 256 threads (4 waves), (256,4): 128-reg budget.
// The whole 128-l chunk lives in registers: bfr[8] (32 VGPR) + w8[8], read from LDS ONCE.
// nt-loop: prefetched A-frag global load, 8 MFMA + 32 sigma (pure VALU), DPP epilogue.
// ZERO DS ops in the hot path.
__global__ __launch_bounds__(256, 4) void k1_scores_v(
    const float* __restrict__ x, const float* __restrict__ xd,
    const float* __restrict__ yd,
    const float* __restrict__ gng, const float* __restrict__ gnb,
    const float* __restrict__ gnm, const float* __restrict__ gnv,
    float* __restrict__ vpart)
{
    __shared__ __align__(16) ushort xd_s[CHUNK][8];   // bf16, pre-scaled, 2 KB
    __shared__ float w_s[CHUNK];                      // 0.5 KB
    __shared__ float wred[4];

    int bid = blockIdx.x;
    int s = bid & (SPLIT - 1);
    int d = (bid >> 3) & 31;
    int b = bid >> 8;
    int tid  = threadIdx.x;
    int lane = tid & 63;
    int wid  = tid >> 6;
    int q    = lane & 15;     // l-col selector within tile
    int g    = lane >> 4;     // k-octet group 0..3 (also p-row group in D)

    float inv_g = gng[d] * rsqrtf(gnv[d] + EPSf);
    float cs    = TWO_LOG2E * inv_g;
    float biasp = TWO_LOG2E * (gnb[d] - gnm[d] * inv_g);
    float Cb    = __builtin_amdgcn_exp2f(biasp);   // bias folded multiplicatively

    float w = 0.f;
    if (tid < CHUNK) {
        int lg = s * CHUNK + tid;
        const float* row = xd + ((size_t)(b * Lq + lg) * Dd + d) * Kk;
        float4 a0 = ((const float4*)row)[0];
        float4 a1 = ((const float4*)row)[1];
        s16x8 rv;
        rv[0] = (short)f2bf(a0.x * cs); rv[1] = (short)f2bf(a0.y * cs);
        rv[2] = (short)f2bf(a0.z * cs); rv[3] = (short)f2bf(a0.w * cs);
        rv[4] = (short)f2bf(a1.x * cs); rv[5] = (short)f2bf(a1.y * cs);
        rv[6] = (short)f2bf(a1.z * cs); rv[7] = (short)f2bf(a1.w * cs);
        *((s16x8*)xd_s[tid]) = rv;
        w = x[((size_t)(b * Lq + lg)) * Dd + d];
        w_s[tid] = w;
    }
    float wsum = w;
    #pragma unroll
    for (int m = 1; m < 64; m <<= 1) wsum += __shfl_xor(wsum, m);
    if (lane == 0) wred[wid] = wsum;
    __syncthreads();
    float S_w = wred[0] + wred[1] + wred[2] + wred[3];

    // ---- hoist the whole chunk into registers (once per wave) ----
    s16x8 bfr[8];
    float w8[8];
    #pragma unroll
    for (int lt = 0; lt < 8; ++lt) {
        bfr[lt] = *((const s16x8*)xd_s[lt * 16 + q]);   // unpredicated broadcast (safe: afr zeros k>=8)
        w8[lt]  = w_s[lt * 16 + q];
    }

    // ---- prefetched A-frag pipeline over 8 nt-tiles ----
    float4 ya = {0,0,0,0}, yb = {0,0,0,0};
    if (g == 0) {
        const float* yr = yd + ((size_t)(b * Pp + wid * 128 + q) * Dd + d) * Kk;
        ya = ((const float4*)yr)[0];
        yb = ((const float4*)yr)[1];
    }

    for (int nt = 0; nt < 8; ++nt) {
        s16x8 afr = {};
        if (g == 0) {
            afr[0] = (short)f2bf(ya.x); afr[1] = (short)f2bf(ya.y);
            afr[2] = (short)f2bf(ya.z); afr[3] = (short)f2bf(ya.w);
            afr[4] = (short)f2bf(yb.x); afr[5] = (short)f2bf(yb.y);
            afr[6] = (short)f2bf(yb.z); afr[7] = (short)f2bf(yb.w);
        }
        float4 yan = {0,0,0,0}, ybn = {0,0,0,0};
        if (nt < 7 && g == 0) {
            const float* yr = yd + ((size_t)(b * Pp + wid * 128 + (nt + 1) * 16 + q) * Dd + d) * Kk;
            yan = ((const float4*)yr)[0];
            ybn = ((const float4*)yr)[1];
        }

        f32x4 acc = {0.f, 0.f, 0.f, 0.f};
        #pragma unroll
        for (int lt = 0; lt < 8; ++lt) {
            f32x4 z = {};
            f32x4 dd = __builtin_amdgcn_mfma_f32_16x16x32_bf16(afr, bfr[lt], z, 0, 0, 0);
            float wl = w8[lt];
            #pragma unroll
            for (int r = 0; r < 4; ++r) {
                float e  = __builtin_amdgcn_exp2f(dd[r]);
                float t  = fmaf(e, Cb, 1.0f);
                float rc = __builtin_amdgcn_rcpf(t);
                acc[r] = fmaf(wl, rc, acc[r]);
            }
        }

        // reduce over l-cols (lanes q=0..15) on the VALU pipe via DPP butterfly
        float4 o;
        #pragma unroll
        for (int r = 0; r < 4; ++r) {
            float v = rowsum16(acc[r]);
            ((float*)&o)[r] = S_w - 2.0f * v;
        }
        if (q == 0) {
            // lane (q=0, g) holds rows p0 + g*4 + (0..3) -> contiguous float4
            size_t base = ((size_t)(s * Bb + b) * Dd + d) * Pp + wid * 128 + nt * 16 + g * 4;
            *(float4*)(vpart + base) = o;
        }
        ya = yan; yb = ybn;
    }
}

// ---------------- Kernel 2: MFMA FFN (unchanged, proven correct) ----------------
__device__ __forceinline__ float gelu_t(float x) {
    float x2 = x * x;
    float up = x * fmaf(x2, 0.10294387f, 2.3022118f);  // 2*log2e*0.79788456*(1, 0.044715)
    float e  = __builtin_amdgcn_exp2f(up);
    float rc = __builtin_amdgcn_rcpf(e + 1.0f);
    return x * (1.0f - rc);
}

__global__ __launch_bounds__(256) void k2_ffn(
    const float* __restrict__ vpart,
    const float* __restrict__ n1g, const float* __restrict__ n1b,
    const float* __restrict__ n1m, const float* __restrict__ n1v,
    const float* __restrict__ w1, const float* __restrict__ b1,
    const float* __restrict__ w2, const float* __restrict__ b2,
    const float* __restrict__ n2g, const float* __restrict__ n2b,
    const float* __restrict__ n2m, const float* __restrict__ n2v,
    float* __restrict__ out)
{
    __shared__ __align__(16) ushort w2l[Dd * Mm];   // 32 KB, W2' bf16, XOR-swizzled
    __shared__ __align__(16) ushort xr_t[32 * 40];  // [p][d] bf16, stride 40 (2.5 KB)
    __shared__ float resid[32 * 33];                // [p][d] f32 (4.2 KB)
    __shared__ float red[4][32 * 33];               // partial out [w][p][d] (16.9 KB)

    int bid = blockIdx.x;
    int b  = bid >> 4;
    int p0 = (bid & 15) * 32;
    int tid  = threadIdx.x;
    int lane = tid & 63;
    int wid  = tid >> 6;
    int lo   = lane & 31;
    int hi   = lane >> 5;

    // ---- stage W2' = w2[d][m] * inv2[d] as bf16, swizzled ----
    {
        int d  = tid >> 3;
        int mb = tid & 7;
        float inv2 = n2g[d] * rsqrtf(n2v[d] + EPSf);
        const float* wr = w2 + (size_t)d * Mm + mb * 64;
        u32 base = (u32)(d * 1024 + mb * 128);
        u32 swz  = (u32)((d & 7) << 4);
        #pragma unroll
        for (int j = 0; j < 8; ++j) {
            float4 f0 = ((const float4*)wr)[j * 2];
            float4 f1 = ((const float4*)wr)[j * 2 + 1];
            uint4 qd;
            qd.x = pack2bf(f0.x * inv2, f0.y * inv2);
            qd.y = pack2bf(f0.z * inv2, f0.w * inv2);
            qd.z = pack2bf(f1.x * inv2, f1.y * inv2);
            qd.w = pack2bf(f1.z * inv2, f1.w * inv2);
            *(uint4*)((char*)w2l + ((base + j * 16) ^ swz)) = qd;
        }
    }

    // ---- phase A: reduce vpart (SPLIT partials) -> n1 -> xr_t(bf16) + resid(f32) ----
    {
        int d  = tid >> 3;
        int pq = tid & 7;
        size_t vb = ((size_t)b * Dd + d) * Pp + p0 + pq * 4;
        float4 sum = {0.f, 0.f, 0.f, 0.f};
        #pragma unroll
        for (int s = 0; s < SPLIT; ++s) {
            float4 t = *(const float4*)(vpart + vb + (size_t)s * (Bb * Dd * Pp));
            sum.x += t.x; sum.y += t.y; sum.z += t.z; sum.w += t.w;
        }
        float inv1 = n1g[d] * rsqrtf(n1v[d] + EPSf);
        float bs1  = n1b[d] - n1m[d] * inv1;
        float inv2 = n2g[d] * rsqrtf(n2v[d] + EPSf);
        float bs2  = n2b[d] - n2m[d] * inv2;
        float b2d  = b2[d];
        float xv[4] = {sum.x, sum.y, sum.z, sum.w};
        #pragma unroll
        for (int j = 0; j < 4; ++j) {
            float xrv = fmaf(xv[j], inv1, bs1);
            int pl = pq * 4 + j;
            xr_t[pl * 40 + d] = f2bf(xrv);
            resid[pl * 33 + d] = fmaf(xrv + b2d, inv2, bs2);
        }
    }
    __syncthreads();

    // ---- phase B+C per wave: h = gelu(W1@xr + b1); out += W2'@h over this wave's m ----
    s16x8 bx0 = *(const s16x8*)((const char*)xr_t + lo * 80 + hi * 16);       // k=d 0..15
    s16x8 bx1 = *(const s16x8*)((const char*)xr_t + lo * 80 + 32 + hi * 16);  // k=d 16..31
    s16x8 bone = {};
    if (hi == 0) bone[0] = (short)0x3F80;   // B[k=32][*] = 1 for bias MFMA

    f32x16 oacc = {};
    #pragma unroll
    for (int i = 0; i < 4; ++i) {
        int mt = wid * 4 + i;
        int m0 = mt * 32;
        const float* w1r = w1 + (size_t)(m0 + lo) * Dd + hi * 8;
        float4 c0 = ((const float4*)w1r)[0];
        float4 c1 = ((const float4*)w1r)[1];
        float4 c2 = ((const float4*)(w1r + 16))[0];
        float4 c3 = ((const float4*)(w1r + 16))[1];
        s16x8 a0, a1;
        a0[0] = (short)f2bf(c0.x); a0[1] = (short)f2bf(c0.y);
        a0[2] = (short)f2bf(c0.z); a0[3] = (short)f2bf(c0.w);
        a0[4] = (short)f2bf(c1.x); a0[5] = (short)f2bf(c1.y);
        a0[6] = (short)f2bf(c1.z); a0[7] = (short)f2bf(c1.w);
        a1[0] = (short)f2bf(c2.x); a1[1] = (short)f2bf(c2.y);
        a1[2] = (short)f2bf(c2.z); a1[3] = (short)f2bf(c2.w);
        a1[4] = (short)f2bf(c3.x); a1[5] = (short)f2bf(c3.y);
        a1[6] = (short)f2bf(c3.z); a1[7] = (short)f2bf(c3.w);
        s16x8 ab = {};
        float b1v = b1[m0 + lo];
        if (hi == 0) ab[0] = (short)f2bf(b1v);   // A[m][k=32] = b1[m]

        f32x16 z = {};
        f32x16 hc = __builtin_amdgcn_mfma_f32_32x32x16_bf16(a0, bx0, z, 0, 0, 0);
        hc = __builtin_amdgcn_mfma_f32_32x32x16_bf16(a1, bx1, hc, 0, 0, 0);
        hc = __builtin_amdgcn_mfma_f32_32x32x16_bf16(ab, bone, hc, 0, 0, 0);

        float gg[16];
        #pragma unroll
        for (int r = 0; r < 16; ++r) gg[r] = gelu_t(hc[r]);

        #pragma unroll
        for (int kt = 0; kt < 2; ++kt) {
            int gb = kt * 8;
            u32 A0 = pack2bf(gg[gb + 0], gg[gb + 1]);
            u32 A1 = pack2bf(gg[gb + 2], gg[gb + 3]);
            u32 A2 = pack2bf(gg[gb + 4], gg[gb + 5]);
            u32 A3 = pack2bf(gg[gb + 6], gg[gb + 7]);
            int lo4 = lo * 4;
            u32 A2lo = (u32)__builtin_amdgcn_ds_bpermute(lo4,       (int)A2);
            u32 A3lo = (u32)__builtin_amdgcn_ds_bpermute(lo4,       (int)A3);
            u32 A0hi = (u32)__builtin_amdgcn_ds_bpermute(lo4 + 128, (int)A0);
            u32 A1hi = (u32)__builtin_amdgcn_ds_bpermute(lo4 + 128, (int)A1);
            union { uint4 u; s16x8 v; } hf;
            hf.u.x = hi ? A2lo : A0;
            hf.u.y = hi ? A3lo : A1;
            hf.u.z = hi ? A2 : A0hi;
            hf.u.w = hi ? A3 : A1hi;
            u32 raddr = (u32)((lo * 1024 + mt * 64 + kt * 32 + hi * 16) ^ ((lo & 7) << 4));
            s16x8 wf = *(const s16x8*)((const char*)w2l + raddr);
            oacc = __builtin_amdgcn_mfma_f32_32x32x16_bf16(wf, hf.v, oacc, 0, 0, 0);
        }
    }

    {
        float* rw = red[wid];
        #pragma unroll
        for (int r = 0; r < 16; ++r) {
            int dr = (r & 3) + ((r >> 2) << 3) + (hi << 2);
            rw[lo * 33 + dr] = oacc[r];
        }
    }
    __syncthreads();

    {
        int d  = tid & 31;
        int pg = tid >> 5;
        #pragma unroll
        for (int j = 0; j < 4; ++j) {
            int pl = pg * 4 + j;
            int idx = pl * 33 + d;
            float v = red[0][idx] + red[1][idx] + red[2][idx] + red[3][idx] + resid[idx];
            out[((size_t)(b * Pp + p0 + pl)) * Dd + d] = v;
        }
    }
}

extern "C" void kernel_launch(void* const* d_in, const int* in_sizes, int n_in,
                              void* d_out, int out_size, void* d_ws, size_t ws_size,
                              hipStream_t stream) {
    const float* x    = (const float*)d_in[0];
    const float* xd   = (const float*)d_in[1];
    const float* yd   = (const float*)d_in[2];
    const float* gng  = (const float*)d_in[3];
    const float* gnb  = (const float*)d_in[4];
    const float* gnm  = (const float*)d_in[5];
    const float* gnv  = (const float*)d_in[6];
    const float* n1g  = (const float*)d_in[7];
    const float* n1b  = (const float*)d_in[8];
    const float* n1m  = (const float*)d_in[9];
    const float* n1v  = (const float*)d_in[10];
    const float* w1   = (const float*)d_in[11];
    const float* b1   = (const float*)d_in[12];
    const float* w2   = (const float*)d_in[13];
    const float* b2   = (const float*)d_in[14];
    const float* n2g  = (const float*)d_in[15];
    const float* n2b  = (const float*)d_in[16];
    const float* n2m  = (const float*)d_in[17];
    const float* n2v  = (const float*)d_in[18];

    float* vpart = (float*)d_ws;   // SPLIT * B * D * P f32 = 4 MB
    float* outf  = (float*)d_out;

    k1_scores_v<<<Bb * Dd * SPLIT, 256, 0, stream>>>(
        x, xd, yd, gng, gnb, gnm, gnv, vpart);
    k2_ffn<<<Bb * (Pp / 32), 256, 0, stream>>>(
        vpart, n1g, n1b, n1m, n1v, w1, b1, w2, b2, n2g, n2b, n2m, n2v, outf);
}